// Round 14
// baseline (829.471 us; speedup 1.0000x reference)
//
#include <hip/hip_runtime.h>
#include <hip/hip_fp16.h>
#include <math.h>

constexpr int N_NODES = 4096;
constexpr int N_EDGES = 65536;
constexpr int D_INF   = 64;
constexpr int H       = 128;
constexpr int T       = 8;
constexpr int B       = 8;
constexpr int M       = B * N_NODES;

typedef __attribute__((ext_vector_type(8))) short bf16x8;
typedef __attribute__((ext_vector_type(4))) float f32x4;
typedef __attribute__((ext_vector_type(8))) _Float16 f16x8;
typedef __attribute__((ext_vector_type(4))) _Float16 f16x4;

__device__ inline unsigned short f2bf(float x) {
  unsigned int u = __float_as_uint(x);
  unsigned int r = (u + 0x7fffu + ((u >> 16) & 1u)) >> 16;
  return (unsigned short)r;
}
__device__ inline float bf2f(unsigned short b) {
  return __uint_as_float((unsigned int)b << 16);
}
// LDS bank swizzle: XOR short-index bits 7-9 into bits 3-5 (bank bits).
__device__ __forceinline__ int swz(int s) { return s ^ (((s >> 7) & 7) << 3); }

// ---------------- CSR build ----------------

__global__ void k_count(const int* __restrict__ dst, int* __restrict__ cnt) {
  int e = blockIdx.x * blockDim.x + threadIdx.x;
  if (e < N_EDGES) atomicAdd(&cnt[dst[e]], 1);
}

__global__ void k_dinv(const int* __restrict__ cnt, float* __restrict__ dinv) {
  int n = blockIdx.x * blockDim.x + threadIdx.x;
  if (n < N_NODES) dinv[n] = 1.0f / sqrtf((float)cnt[n] + 2.0f);
}

__global__ void k_scan(const int* __restrict__ cnt, int* __restrict__ rowptr) {
  __shared__ int sums[1024];
  int t = threadIdx.x;
  int v0 = cnt[4*t+0], v1 = cnt[4*t+1], v2 = cnt[4*t+2], v3 = cnt[4*t+3];
  int s0 = v0, s1 = s0 + v1, s2 = s1 + v2, s3 = s2 + v3;
  sums[t] = s3;
  __syncthreads();
  for (int off = 1; off < 1024; off <<= 1) {
    int x = (t >= off) ? sums[t - off] : 0;
    __syncthreads();
    sums[t] += x;
    __syncthreads();
  }
  int base = (t > 0) ? sums[t - 1] : 0;
  if (t == 0) rowptr[0] = 0;
  rowptr[4*t+1] = base + s0;
  rowptr[4*t+2] = base + s1;
  rowptr[4*t+3] = base + s2;
  rowptr[4*t+4] = base + s3;
}

__global__ void k_fill(const int* __restrict__ src, const int* __restrict__ dst,
                       const float* __restrict__ dinv, const int* __restrict__ rowptr,
                       int* __restrict__ fill, int2* __restrict__ eg) {
  int e = blockIdx.x * blockDim.x + threadIdx.x;
  if (e >= N_EDGES) return;
  int s = src[e], d = dst[e];
  int p = rowptr[d] + atomicAdd(&fill[d], 1);
  eg[p] = make_int2(s, __float_as_int(dinv[s] * dinv[d]));
}

// ---- degree counting sort (work balance only; output unchanged) ----
__global__ void k_hist(const int* __restrict__ cnt, int* __restrict__ hist) {
  int n = blockIdx.x * blockDim.x + threadIdx.x;
  if (n < N_NODES) atomicAdd(&hist[min(cnt[n], 127)], 1);
}

__global__ void k_hscan(const int* __restrict__ hist, int* __restrict__ hbase) {
  __shared__ int sh[128];
  int t = threadIdx.x;
  sh[t] = hist[t];
  __syncthreads();
  for (int off = 1; off < 128; off <<= 1) {
    int x = (t >= off) ? sh[t - off] : 0;
    __syncthreads();
    sh[t] += x;
    __syncthreads();
  }
  hbase[t] = sh[t] - hist[t];
}

__global__ void k_place(const int* __restrict__ cnt, const int* __restrict__ hbase,
                        int* __restrict__ filld, int* __restrict__ sorted) {
  int n = blockIdx.x * blockDim.x + threadIdx.x;
  if (n >= N_NODES) return;
  int d = min(cnt[n], 127);
  sorted[hbase[d] + atomicAdd(&filld[d], 1)] = n;
}

// ---------------- W pack: gate-interleaved cols + MFMA fragment order + hi/lo ----
__global__ void k_pack(const float* __restrict__ W, unsigned short* __restrict__ Bp,
                       int K) {
  int tid = blockIdx.x * 256 + threadIdx.x;
  if (tid >= K * 64) return;
  int lane = tid & 63;
  int ntg  = (tid >> 6) & 31;
  int kb   = tid >> 11;
  int gate = ntg & 3, fg = ntg >> 2;
  int corig = gate * 128 + fg * 16 + (lane & 15);
  int k0 = kb * 32 + (lane >> 4) * 8;
  long obase = ((long)(kb * 32 + ntg) * 64 + lane) * 8;
  long plane = (long)K * 512;
  #pragma unroll
  for (int j = 0; j < 8; ++j) {
    float v = W[(long)(k0 + j) * 512 + corig];
    unsigned short h = f2bf(v);
    Bp[obase + j]         = h;
    Bp[plane + obase + j] = f2bf(v - bf2f(h));
  }
}

// ---------------- k_ax: precompute AX[t][b][n][64] = (A_hat @ x_t) as fp16 ----
__global__ __launch_bounds__(256) void k_ax(
    const int* __restrict__ rowptr, const int2* __restrict__ eg,
    const float* __restrict__ dinv, const float* __restrict__ x,
    _Float16* __restrict__ AX) {
  int tid = threadIdx.x;
  int grp = blockIdx.x * 16 + (tid >> 4);   // 262144 groups
  int l   = tid & 15;
  int c4  = l * 4;
  int n   = grp & (N_NODES - 1);
  int bt  = grp >> 12;
  int b   = bt & 7, tt = bt >> 3;
  const float* Xb = x + (long)(b * T + tt) * N_NODES * D_INF;
  float acc[4] = {0.f, 0.f, 0.f, 0.f};
  int rs = rowptr[n], re = rowptr[n + 1];
  int e = rs;
  for (; e + 3 < re; e += 4) {
    int2 q0 = eg[e], q1 = eg[e + 1], q2 = eg[e + 2], q3 = eg[e + 3];
    float w0 = __int_as_float(q0.y), w1 = __int_as_float(q1.y);
    float w2 = __int_as_float(q2.y), w3 = __int_as_float(q3.y);
    f32x4 a0 = *(const f32x4*)(Xb + (long)q0.x * D_INF + c4);
    f32x4 a1 = *(const f32x4*)(Xb + (long)q1.x * D_INF + c4);
    f32x4 a2 = *(const f32x4*)(Xb + (long)q2.x * D_INF + c4);
    f32x4 a3 = *(const f32x4*)(Xb + (long)q3.x * D_INF + c4);
    #pragma unroll
    for (int q = 0; q < 4; ++q)
      acc[q] += w0 * a0[q] + w1 * a1[q] + w2 * a2[q] + w3 * a3[q];
  }
  for (; e < re; ++e) {
    int2 q0 = eg[e];
    float w0 = __int_as_float(q0.y);
    f32x4 a0 = *(const f32x4*)(Xb + (long)q0.x * D_INF + c4);
    #pragma unroll
    for (int q = 0; q < 4; ++q) acc[q] += w0 * a0[q];
  }
  float dn = dinv[n];
  float sw = 2.0f * dn * dn;
  f32x4 a = *(const f32x4*)(Xb + (long)n * D_INF + c4);
  #pragma unroll
  for (int q = 0; q < 4; ++q) acc[q] += sw * a[q];
  f16x4 o;
  #pragma unroll
  for (int q = 0; q < 4; ++q) o[q] = (_Float16)acc[q];
  *(f16x4*)(AX + ((long)(tt * 8 + b) * N_NODES + n) * D_INF + c4) = o;
}

// ---------------- k_l0: layer 0 step, NO gather ----------------
// A = [AX_t stripe (kb 0-1, from LDS) | AH0 fragments (kb 2-5, direct global)].
// Same sorted-pair row mapping as k_l1 so AH0 fragments line up.
__global__ __launch_bounds__(512, 4) void k_l0(
    const int* __restrict__ sorted,
    const _Float16* __restrict__ AXt,        // [b][n][64] fp16 (this t)
    const unsigned short* __restrict__ AH0,  // [512][8pm][4kb][64][8] bf16 frags
    const unsigned short* __restrict__ Bp, const float* __restrict__ bias,
    _Float16* __restrict__ hout, float* __restrict__ cbuf) {
  __shared__ __align__(16) unsigned short Atx[8 * 2 * 64 * 8];  // 16 KB
  __shared__ int nodeLDS[64];
  int tid  = threadIdx.x;
  int lane = tid & 63;
  int w    = tid >> 6;
  int j    = blockIdx.x;
  int b    = j & 7;
  int jj   = j >> 3;
  int g    = lane >> 4, l = lane & 15;
  int c4   = l * 4;
  int kbA32  = c4 >> 5;
  int subA32 = (l & 7) >> 1;
  int j0A32  = (l & 1) * 4;

  // phase 1: tiny — read AX rows, split, stage 16 KB LDS
  #pragma unroll
  for (int nd = 0; nd < 2; ++nd) {
    int r = (w << 3) + (g << 1) + nd;
    int pairIdx = jj * 32 + (r >> 1);
    int n = (r & 1) ? sorted[N_NODES - 1 - pairIdx] : sorted[pairIdx];
    if (l == 0) nodeLDS[r] = n;
    f16x4 xv = *(const f16x4*)(AXt + ((long)b * N_NODES + n) * D_INF + c4);
    unsigned long long hv = 0ull, lv = 0ull;
    #pragma unroll
    for (int q = 0; q < 4; ++q) {
      float a = (float)xv[q];
      unsigned short hs = f2bf(a);
      unsigned short ls = f2bf(a - bf2f(hs));
      hv |= (unsigned long long)hs << (16 * q);
      lv |= (unsigned long long)ls << (16 * q);
    }
    int mt = r >> 4;
    int lA = (r & 15) + 16 * subA32;
    *(unsigned long long*)(Atx + swz(((mt * 2 + kbA32) * 64 + lA) * 8 + j0A32)) = hv;
    *(unsigned long long*)(Atx + swz((((4 + mt) * 2 + kbA32) * 64 + lA) * 8 + j0A32)) = lv;
  }
  __syncthreads();

  // phase 2: K=192, kb 0-1 from LDS, kb 2-5 from global AH0 fragments
  int l15 = lane & 15, lq = lane >> 4;
  const unsigned short* bb  = Bp + (long)(w * 4) * 512 + lane * 8;
  const unsigned short* blp = bb + (long)192 * 512;

  f32x4 acc[4][4];
  #pragma unroll
  for (int mt = 0; mt < 4; ++mt)
    #pragma unroll
    for (int gt = 0; gt < 4; ++gt)
      acc[mt][gt] = (f32x4){0.f, 0.f, 0.f, 0.f};

  __builtin_amdgcn_s_setprio(1);
  #pragma unroll
  for (int kb = 0; kb < 6; ++kb) {
    bf16x8 AH_[4], AL_[4];
    if (kb < 2) {
      #pragma unroll
      for (int mt = 0; mt < 4; ++mt) {
        AH_[mt] = *(const bf16x8*)(Atx + swz(((mt * 2 + kb) * 64 + lane) * 8));
        AL_[mt] = *(const bf16x8*)(Atx + swz((((4 + mt) * 2 + kb) * 64 + lane) * 8));
      }
    } else {
      #pragma unroll
      for (int mt = 0; mt < 4; ++mt) {
        AH_[mt] = *(const bf16x8*)(AH0 + ((((long)j * 8 + mt) * 4 + (kb - 2)) * 64 + lane) * 8);
        AL_[mt] = *(const bf16x8*)(AH0 + ((((long)j * 8 + 4 + mt) * 4 + (kb - 2)) * 64 + lane) * 8);
      }
    }
    bf16x8 BH[4], BL[4];
    #pragma unroll
    for (int gt = 0; gt < 4; ++gt) {
      BH[gt] = *(const bf16x8*)(bb  + ((long)kb * 32 + gt) * 512);
      BL[gt] = *(const bf16x8*)(blp + ((long)kb * 32 + gt) * 512);
    }
    #pragma unroll
    for (int gt = 0; gt < 4; ++gt) {
      #pragma unroll
      for (int mt = 0; mt < 4; ++mt) {
        acc[mt][gt] = __builtin_amdgcn_mfma_f32_16x16x32_bf16(AH_[mt], BH[gt], acc[mt][gt], 0, 0, 0);
        acc[mt][gt] = __builtin_amdgcn_mfma_f32_16x16x32_bf16(AL_[mt], BH[gt], acc[mt][gt], 0, 0, 0);
        acc[mt][gt] = __builtin_amdgcn_mfma_f32_16x16x32_bf16(AH_[mt], BL[gt], acc[mt][gt], 0, 0, 0);
      }
    }
  }
  __builtin_amdgcn_s_setprio(0);

  int f = w * 16 + l15;
  float bi = bias[f], bff = bias[128 + f], bo = bias[256 + f], bg = bias[384 + f];
  #pragma unroll
  for (int mt = 0; mt < 4; ++mt) {
    #pragma unroll
    for (int r = 0; r < 4; ++r) {
      int rt = mt * 16 + lq * 4 + r;
      int n2 = nodeLDS[rt];
      float vi = 1.0f / (1.0f + __expf(-(acc[mt][0][r] + bi)));
      float vf = 1.0f / (1.0f + __expf(-(acc[mt][1][r] + bff)));
      float vo = 1.0f / (1.0f + __expf(-(acc[mt][2][r] + bo)));
      float vg = tanhf(acc[mt][3][r] + bg);
      long idx = ((long)b * N_NODES + n2) * H + f;
      float cn = vf * cbuf[idx] + vi * vg;
      float hn = vo * tanhf(cn);
      cbuf[idx] = cn;
      hout[idx] = (_Float16)hn;
    }
  }
}

// ---------------- k_l1: layer 1 step (gathers h0,h1; dumps AH0 fragments) ----
__global__ __launch_bounds__(512, 4) void k_l1(
    const int* __restrict__ rowptr, const int2* __restrict__ eg,
    const float* __restrict__ dinv, const int* __restrict__ sorted,
    const _Float16* __restrict__ H0,     // h0(t) node-order
    const _Float16* __restrict__ H1r,    // h1(t-1)
    const unsigned short* __restrict__ Bp, const float* __restrict__ bias,
    unsigned short* __restrict__ AH0,    // fragment dump for L0@t+1
    _Float16* __restrict__ h1out, float* __restrict__ cbuf,
    float* __restrict__ out2, int t) {
  constexpr int KB = 8;
  __shared__ __align__(16) unsigned short At[8 * KB * 64 * 8];  // 64 KB
  __shared__ int nodeLDS[64];
  int tid  = threadIdx.x;
  int lane = tid & 63;
  int w    = tid >> 6;
  int j    = blockIdx.x;
  int b    = j & 7;
  int jj   = j >> 3;
  int g    = lane >> 4, l = lane & 15;
  int c8   = l * 8;
  const _Float16* A_p = H0  + (long)b * N_NODES * H;
  const _Float16* B_p = H1r + (long)b * N_NODES * H;
  int lane2f = 16 * (l & 3);
  int kbA16  = c8 >> 5;          // 0..3
  int kbB    = 4 + kbA16;        // 4..7

  #pragma unroll
  for (int nd = 0; nd < 2; ++nd) {
    int r  = (w << 3) + (g << 1) + nd;
    int pairIdx = jj * 32 + (r >> 1);
    int n  = (r & 1) ? sorted[N_NODES - 1 - pairIdx] : sorted[pairIdx];
    if (l == 0) nodeLDS[r] = n;
    int rs = rowptr[n], re = rowptr[n + 1];
    float accA[8] = {0.f,0.f,0.f,0.f,0.f,0.f,0.f,0.f};
    float accB[8] = {0.f,0.f,0.f,0.f,0.f,0.f,0.f,0.f};
    int e = rs;
    for (; e + 3 < re; e += 4) {
      int2 q0 = eg[e], q1 = eg[e + 1], q2 = eg[e + 2], q3 = eg[e + 3];
      float w0 = __int_as_float(q0.y), w1 = __int_as_float(q1.y);
      float w2 = __int_as_float(q2.y), w3 = __int_as_float(q3.y);
      f16x8 a0 = *(const f16x8*)(A_p + (long)q0.x * H + c8);
      f16x8 a1 = *(const f16x8*)(A_p + (long)q1.x * H + c8);
      f16x8 a2 = *(const f16x8*)(A_p + (long)q2.x * H + c8);
      f16x8 a3 = *(const f16x8*)(A_p + (long)q3.x * H + c8);
      #pragma unroll
      for (int q = 0; q < 8; ++q)
        accA[q] += w0 * (float)a0[q] + w1 * (float)a1[q]
                 + w2 * (float)a2[q] + w3 * (float)a3[q];
      f16x8 b0 = *(const f16x8*)(B_p + (long)q0.x * H + c8);
      f16x8 b1 = *(const f16x8*)(B_p + (long)q1.x * H + c8);
      f16x8 b2 = *(const f16x8*)(B_p + (long)q2.x * H + c8);
      f16x8 b3 = *(const f16x8*)(B_p + (long)q3.x * H + c8);
      #pragma unroll
      for (int q = 0; q < 8; ++q)
        accB[q] += w0 * (float)b0[q] + w1 * (float)b1[q]
                 + w2 * (float)b2[q] + w3 * (float)b3[q];
    }
    for (; e < re; ++e) {
      int2 q0 = eg[e];
      float w0 = __int_as_float(q0.y);
      f16x8 a0 = *(const f16x8*)(A_p + (long)q0.x * H + c8);
      #pragma unroll
      for (int q = 0; q < 8; ++q) accA[q] += w0 * (float)a0[q];
      f16x8 b0 = *(const f16x8*)(B_p + (long)q0.x * H + c8);
      #pragma unroll
      for (int q = 0; q < 8; ++q) accB[q] += w0 * (float)b0[q];
    }
    float dn = dinv[n];
    float sw = 2.0f * dn * dn;
    {
      f16x8 a = *(const f16x8*)(A_p + (long)n * H + c8);
      f16x8 v = *(const f16x8*)(B_p + (long)n * H + c8);
      #pragma unroll
      for (int q = 0; q < 8; ++q) {
        accA[q] += sw * (float)a[q];
        accB[q] += sw * (float)v[q];
      }
    }

    int mt    = r >> 4;
    int lane2 = (r & 15) + lane2f;
    // plane B (h1)
    {
      bf16x8 hv, lv;
      #pragma unroll
      for (int q = 0; q < 8; ++q) {
        unsigned short hs = f2bf(accB[q]);
        hv[q] = (short)hs;
        lv[q] = (short)f2bf(accB[q] - bf2f(hs));
      }
      *(bf16x8*)(At + swz((((mt)     * KB + kbB) * 64 + lane2) * 8)) = hv;
      *(bf16x8*)(At + swz((((4 + mt) * KB + kbB) * 64 + lane2) * 8)) = lv;
    }
    // plane A (h0): LDS + global AH0 dump for L0@t+1
    {
      bf16x8 hv, lv;
      #pragma unroll
      for (int q = 0; q < 8; ++q) {
        unsigned short hs = f2bf(accA[q]);
        hv[q] = (short)hs;
        lv[q] = (short)f2bf(accA[q] - bf2f(hs));
      }
      *(bf16x8*)(At + swz((((mt)     * KB + kbA16) * 64 + lane2) * 8)) = hv;
      *(bf16x8*)(At + swz((((4 + mt) * KB + kbA16) * 64 + lane2) * 8)) = lv;
      *(bf16x8*)(AH0 + ((((long)j * 8 + mt)     * 4 + kbA16) * 64 + lane2) * 8) = hv;
      *(bf16x8*)(AH0 + ((((long)j * 8 + 4 + mt) * 4 + kbA16) * 64 + lane2) * 8) = lv;
    }
  }
  __syncthreads();

  // phase 2: K=256 MFMA + LSTM
  int l15 = lane & 15, lq = lane >> 4;
  const unsigned short* bb  = Bp + (long)(w * 4) * 512 + lane * 8;
  const unsigned short* blp = bb + (long)256 * 512;

  f32x4 acc[4][4];
  #pragma unroll
  for (int mt = 0; mt < 4; ++mt)
    #pragma unroll
    for (int gt = 0; gt < 4; ++gt)
      acc[mt][gt] = (f32x4){0.f, 0.f, 0.f, 0.f};

  __builtin_amdgcn_s_setprio(1);
  #pragma unroll 2
  for (int kb = 0; kb < KB; ++kb) {
    bf16x8 AH_[4], AL_[4];
    #pragma unroll
    for (int mt = 0; mt < 4; ++mt) {
      AH_[mt] = *(const bf16x8*)(At + swz((((mt)     * KB + kb) * 64 + lane) * 8));
      AL_[mt] = *(const bf16x8*)(At + swz((((4 + mt) * KB + kb) * 64 + lane) * 8));
    }
    bf16x8 BH[4], BL[4];
    #pragma unroll
    for (int gt = 0; gt < 4; ++gt) {
      BH[gt] = *(const bf16x8*)(bb  + ((long)kb * 32 + gt) * 512);
      BL[gt] = *(const bf16x8*)(blp + ((long)kb * 32 + gt) * 512);
    }
    #pragma unroll
    for (int gt = 0; gt < 4; ++gt) {
      #pragma unroll
      for (int mt = 0; mt < 4; ++mt) {
        acc[mt][gt] = __builtin_amdgcn_mfma_f32_16x16x32_bf16(AH_[mt], BH[gt], acc[mt][gt], 0, 0, 0);
        acc[mt][gt] = __builtin_amdgcn_mfma_f32_16x16x32_bf16(AL_[mt], BH[gt], acc[mt][gt], 0, 0, 0);
        acc[mt][gt] = __builtin_amdgcn_mfma_f32_16x16x32_bf16(AH_[mt], BL[gt], acc[mt][gt], 0, 0, 0);
      }
    }
  }
  __builtin_amdgcn_s_setprio(0);

  int f = w * 16 + l15;
  float bi = bias[f], bff = bias[128 + f], bo = bias[256 + f], bg = bias[384 + f];
  #pragma unroll
  for (int mt = 0; mt < 4; ++mt) {
    #pragma unroll
    for (int r = 0; r < 4; ++r) {
      int rt = mt * 16 + lq * 4 + r;
      int n2 = nodeLDS[rt];
      float vi = 1.0f / (1.0f + __expf(-(acc[mt][0][r] + bi)));
      float vf = 1.0f / (1.0f + __expf(-(acc[mt][1][r] + bff)));
      float vo = 1.0f / (1.0f + __expf(-(acc[mt][2][r] + bo)));
      float vg = tanhf(acc[mt][3][r] + bg);
      long idx = ((long)b * N_NODES + n2) * H + f;
      float cn = vf * cbuf[idx] + vi * vg;
      float hn = vo * tanhf(cn);
      cbuf[idx] = cn;
      h1out[idx] = (_Float16)hn;
      __builtin_nontemporal_store(hn,
          &out2[(((long)b * T + t) * N_NODES + n2) * H + f]);
    }
  }
}

// ---------------- launch ----------------

extern "C" void kernel_launch(void* const* d_in, const int* in_sizes, int n_in,
                              void* d_out, int out_size, void* d_ws, size_t ws_size,
                              hipStream_t stream) {
  const float* x  = (const float*)d_in[0];
  const float* W0 = (const float*)d_in[1];
  const float* b0 = (const float*)d_in[2];
  const float* W1 = (const float*)d_in[3];
  const float* b1 = (const float*)d_in[4];
  const int*   ei = (const int*)d_in[5];
  const int* srcp = ei;
  const int* dstp = ei + N_EDGES;
  float* out = (float*)d_out;

  char* p = (char*)d_ws;
  auto alloc = [&](size_t bytes) {
    char* r = p;
    p += (bytes + 255) & ~(size_t)255;
    return r;
  };
  int*   cnt    = (int*)  alloc(N_NODES * 4);
  int*   fill   = (int*)  alloc(N_NODES * 4);
  float* dinv   = (float*)alloc(N_NODES * 4);
  int*   rowptr = (int*)  alloc((N_NODES + 1) * 4);
  int2*  eg     = (int2*) alloc((size_t)N_EDGES * 8);
  int*   hist   = (int*)  alloc(128 * 4);
  int*   hbase  = (int*)  alloc(128 * 4);
  int*   filld  = (int*)  alloc(128 * 4);
  int*   sorted = (int*)  alloc(N_NODES * 4);
  float* cc     = (float*)alloc((size_t)2 * M * H * 4);        // c0,c1 fp32
  _Float16* hh  = (_Float16*)alloc((size_t)3 * M * H * 2);     // h0, h1 x2
  _Float16* AX  = (_Float16*)alloc((size_t)T * M * D_INF * 2); // 33.5 MB
  unsigned short* AH0 = (unsigned short*)alloc((size_t)512 * 8 * 4 * 64 * 8 * 2); // 16.8 MB
  unsigned short* Bp0 = (unsigned short*)alloc((size_t)192 * 512 * 2 * 2);
  unsigned short* Bp1 = (unsigned short*)alloc((size_t)256 * 512 * 2 * 2);
  float*    c0  = cc;
  float*    c1  = cc + (size_t)M * H;
  _Float16* h0  = hh;
  _Float16* h1a = hh + (size_t)M * H;
  _Float16* h1b = hh + (size_t)2 * M * H;

  hipMemsetAsync(cnt,   0, N_NODES * 4, stream);
  hipMemsetAsync(fill,  0, N_NODES * 4, stream);
  hipMemsetAsync(hist,  0, 128 * 4, stream);
  hipMemsetAsync(filld, 0, 128 * 4, stream);
  hipMemsetAsync(cc,    0, (size_t)2 * M * H * 4, stream);
  hipMemsetAsync(hh,    0, (size_t)3 * M * H * 2, stream);
  hipMemsetAsync(AH0,   0, (size_t)512 * 8 * 4 * 64 * 8 * 2, stream);

  k_count<<<N_EDGES / 256, 256, 0, stream>>>(dstp, cnt);
  k_dinv <<<N_NODES / 256, 256, 0, stream>>>(cnt, dinv);
  k_scan <<<1, 1024, 0, stream>>>(cnt, rowptr);
  k_fill <<<N_EDGES / 256, 256, 0, stream>>>(srcp, dstp, dinv, rowptr, fill, eg);
  k_hist <<<N_NODES / 256, 256, 0, stream>>>(cnt, hist);
  k_hscan<<<1, 128, 0, stream>>>(hist, hbase);
  k_place<<<N_NODES / 256, 256, 0, stream>>>(cnt, hbase, filld, sorted);
  k_pack <<<(192 * 64 + 255) / 256, 256, 0, stream>>>(W0, Bp0, 192);
  k_pack <<<(256 * 64 + 255) / 256, 256, 0, stream>>>(W1, Bp1, 256);
  k_ax   <<<(8 * T * N_NODES) / 16, 256, 0, stream>>>(rowptr, eg, dinv, x, AX);

  for (int t = 0; t < T; ++t) {
    const _Float16* h1r = (t & 1) ? h1b : h1a;
    _Float16*       h1w = (t & 1) ? h1a : h1b;
    k_l0<<<512, 512, 0, stream>>>(sorted,
        AX + (size_t)t * M * D_INF, AH0, Bp0, b0, h0, c0);
    k_l1<<<512, 512, 0, stream>>>(rowptr, eg, dinv, sorted,
        h0, h1r, Bp1, b1, AH0, h1w, c1, out, t);
  }
}